// Round 1
// baseline (723.566 us; speedup 1.0000x reference)
//
#include <hip/hip_runtime.h>
#include <math.h>

#define T_DIM 5
#define Z_DIM 32
#define Y_DIM 512
#define X_DIM 512
#define N_RAYS 10000
#define N_STEPS 768
#define STEPS_PER_LANE 12   // 768 / 64 lanes
#define VOXEL_F 0.2f

__global__ void zero_ws_kernel(float* ws) {
    if (threadIdx.x < 8) ws[threadIdx.x] = 0.0f;
}

// One wave (64 lanes) per ray; lane L handles steps [12L, 12L+12).
__global__ __launch_bounds__(256) void render_rays_kernel(
    const float* __restrict__ grid,     // [T,Z,Y,X] raw feats (relu applied here)
    const float* __restrict__ origin,   // [T,3] meters
    const float* __restrict__ points,   // [N_RAYS,3] meters
    const int*   __restrict__ tindex,   // [N_RAYS]
    float*       __restrict__ ws)       // [0]=sum|d| [1]=sum .5 d^2 [2]=sum absrel [3]=count
{
    const int wave = (int)((blockIdx.x * blockDim.x + threadIdx.x) >> 6);
    const int lane = (int)(threadIdx.x & 63);
    if (wave >= N_RAYS) return;
    const int ray = wave;

    const int ti = tindex[ray];
    // meters -> voxel coords: (v - offset) / 0.2 == (v - offset) * 5
    const float ox = (origin[ti * 3 + 0] + 51.2f) * 5.0f;
    const float oy = (origin[ti * 3 + 1] + 51.2f) * 5.0f;
    const float oz = (origin[ti * 3 + 2] + 3.2f) * 5.0f;
    const float px = (points[ray * 3 + 0] + 51.2f) * 5.0f;
    const float py = (points[ray * 3 + 1] + 51.2f) * 5.0f;
    const float pz = (points[ray * 3 + 2] + 3.2f) * 5.0f;

    const float dx = px - ox, dy = py - oy, dz = pz - oz;
    const float gt_vox = sqrtf(dx * dx + dy * dy + dz * dz);
    const float inv = 1.0f / fmaxf(gt_vox, 1e-6f);
    const float ux = dx * inv, uy = dy * inv, uz = dz * inv;

    const float* gbase = grid + (size_t)ti * (size_t)(Z_DIM * Y_DIM * X_DIM);

    float local_tau   = 0.0f;   // sum of tau in this lane's chunk
    float local_trans = 1.0f;   // exp(-local cumulative tau)
    float local_pred  = 0.0f;   // sum of local_trans*(1-e)*t within chunk

    const int s0 = lane * STEPS_PER_LANE;
#pragma unroll
    for (int j = 0; j < STEPS_PER_LANE; ++j) {
        const float tt = (float)(s0 + j) + 0.5f;
        const float fx = ox + ux * tt;
        const float fy = oy + uy * tt;
        const float fz = oz + uz * tt;
        const int ix = (int)floorf(fx);
        const int iy = (int)floorf(fy);
        const int iz = (int)floorf(fz);
        const bool inb = (ix >= 0) & (ix < X_DIM) & (iy >= 0) & (iy < Y_DIM) &
                         (iz >= 0) & (iz < Z_DIM);
        float tau = 0.0f;
        if (inb) {
            const float s = gbase[((size_t)iz * Y_DIM + (size_t)iy) * X_DIM + (size_t)ix];
            tau = fmaxf(s, 0.0f);   // relu
        }
        const float e = expf(-tau);
        local_pred += local_trans * (1.0f - e) * tt;
        local_trans *= e;
        local_tau += tau;
    }

    // Exclusive prefix sum of local_tau across the 64 lanes.
    float scan = local_tau;
#pragma unroll
    for (int d = 1; d < 64; d <<= 1) {
        const float up = __shfl_up(scan, d, 64);
        if (lane >= d) scan += up;
    }
    const float excl = scan - local_tau;

    // This lane's contribution to the ray's expected distance.
    float contrib = expf(-excl) * local_pred;

    // Wave-wide sum (butterfly).
#pragma unroll
    for (int d = 32; d >= 1; d >>= 1) contrib += __shfl_xor(contrib, d, 64);

    if (lane == 0) {
        const float pred_m = contrib * VOXEL_F;
        const float gt_m   = gt_vox * VOXEL_F;
        if (gt_m >= 0.0f) {
            const float diff = gt_m - pred_m;
            const float ad   = fabsf(diff);
            atomicAdd(&ws[0], ad);
            atomicAdd(&ws[1], 0.5f * diff * diff);
            atomicAdd(&ws[2], ad / fmaxf(gt_m, 1e-6f));
            atomicAdd(&ws[3], 1.0f);
        }
    }
}

__global__ void finalize_kernel(const float* __restrict__ ws, float* __restrict__ out) {
    if (threadIdx.x == 0) {
        const float cnt = fmaxf(ws[3], 1.0f);
        out[0] = ws[0] / cnt;
        out[1] = ws[1] / cnt;
        out[2] = ws[2] / cnt;
    }
}

extern "C" void kernel_launch(void* const* d_in, const int* in_sizes, int n_in,
                              void* d_out, int out_size, void* d_ws, size_t ws_size,
                              hipStream_t stream) {
    const float* grid    = (const float*)d_in[0];   // (1,5,32,512,512) fp32
    const float* origin  = (const float*)d_in[1];   // (1,5,3) fp32
    const float* points  = (const float*)d_in[2];   // (1,10000,3) fp32
    const int*   tindex  = (const int*)d_in[3];     // (1,10000) int32
    float* out = (float*)d_out;
    float* ws  = (float*)d_ws;

    zero_ws_kernel<<<1, 64, 0, stream>>>(ws);

    const int waves_per_block = 256 / 64;                       // 4 rays per block
    const int blocks = (N_RAYS + waves_per_block - 1) / waves_per_block;  // 2500
    render_rays_kernel<<<blocks, 256, 0, stream>>>(grid, origin, points, tindex, ws);

    finalize_kernel<<<1, 64, 0, stream>>>(ws, out);
}

// Round 2
// 275.806 us; speedup vs baseline: 2.6235x; 2.6235x over previous
//
#include <hip/hip_runtime.h>
#include <math.h>

#define T_DIM 5
#define Z_DIM 32
#define Y_DIM 512
#define X_DIM 512
#define N_RAYS 10000
#define N_STEPS 768
#define VOXEL_F 0.2f
#define NBUCKET 64   // loss-accumulator buckets (x4 floats each)

__global__ void zero_ws_kernel(float* ws) {
    const int i = blockIdx.x * blockDim.x + threadIdx.x;
    if (i < NBUCKET * 4) ws[i] = 0.0f;
}

// One wave per ray. Iteration j covers steps [64j, 64j+64): lane L handles
// step 64j+L -> one wave gather reads 64 CONSECUTIVE voxels along the ray.
// Loop bounded by analytic box exit; early-out when transmittance < 1e-7.
__global__ __launch_bounds__(256) void render_rays_kernel(
    const float* __restrict__ grid,     // [T,Z,Y,X] raw feats (relu here)
    const float* __restrict__ origin,   // [T,3] meters
    const float* __restrict__ points,   // [N_RAYS,3] meters
    const int*   __restrict__ tindex,   // [N_RAYS]
    float*       __restrict__ ws)       // NBUCKET x {sum|d|, .5d^2, absrel, count}
{
    const int wid  = (int)((blockIdx.x * blockDim.x + threadIdx.x) >> 6);
    const int lane = (int)(threadIdx.x & 63);
    if (wid >= N_RAYS) return;
    const int ray = wid;

    const int ti = tindex[ray];
    const float ox = (origin[ti * 3 + 0] + 51.2f) * 5.0f;
    const float oy = (origin[ti * 3 + 1] + 51.2f) * 5.0f;
    const float oz = (origin[ti * 3 + 2] + 3.2f) * 5.0f;
    const float px = (points[ray * 3 + 0] + 51.2f) * 5.0f;
    const float py = (points[ray * 3 + 1] + 51.2f) * 5.0f;
    const float pz = (points[ray * 3 + 2] + 3.2f) * 5.0f;

    const float dx = px - ox, dy = py - oy, dz = pz - oz;
    const float gt_vox = sqrtf(dx * dx + dy * dy + dz * dz);
    const float inv = 1.0f / fmaxf(gt_vox, 1e-6f);
    const float ux = dx * inv, uy = dy * inv, uz = dz * inv;

    // Analytic exit t from the in-bounds box [0,X)x[0,Y)x[0,Z).
    // Origin is inside (setup guarantees it), so in-bounds steps are [0, thi).
    // fmaxf of the two signed crossings picks the positive (exit) one; /0 -> inf
    // handled by IEEE; NaN (0/0) discarded by fmaxf. Per-step inb check below
    // still guards all edge cases exactly.
    float thi = 1e30f;
    thi = fminf(thi, fmaxf((0.0f - ox) / ux, ((float)X_DIM - ox) / ux));
    thi = fminf(thi, fmaxf((0.0f - oy) / uy, ((float)Y_DIM - oy) / uy));
    thi = fminf(thi, fmaxf((0.0f - oz) / uz, ((float)Z_DIM - oz) / uz));
    int n_active = (int)ceilf(fminf(thi, 769.0f) - 0.5f);  // steps k with k+0.5 < thi
    n_active = min(N_STEPS, max(0, n_active));
    const int iters = (n_active + 63) >> 6;

    const float* gbase = grid + (size_t)ti * (size_t)(Z_DIM * Y_DIM * X_DIM);

    float lane_acc = 0.0f;   // sum of this lane's weighted-t contributions
    float ecarry   = 1.0f;   // exp(-sum tau of all previous 64-step chunks), wave-uniform

    for (int j = 0; j < iters; ++j) {
        const int step = (j << 6) + lane;
        const float tt = (float)step + 0.5f;
        const float fx = fmaf(ux, tt, ox);
        const float fy = fmaf(uy, tt, oy);
        const float fz = fmaf(uz, tt, oz);
        const int ix = (int)floorf(fx);
        const int iy = (int)floorf(fy);
        const int iz = (int)floorf(fz);
        const bool inb = (ix >= 0) & (ix < X_DIM) & (iy >= 0) & (iy < Y_DIM) &
                         (iz >= 0) & (iz < Z_DIM);
        float tau = 0.0f;
        if ((step < n_active) && inb) {
            tau = fmaxf(gbase[((size_t)iz * Y_DIM + (size_t)iy) * X_DIM + (size_t)ix], 0.0f);
        }

        // Inclusive prefix sum of tau across the 64 lanes (steps are lane-ordered).
        float scan = tau;
#pragma unroll
        for (int d = 1; d < 64; d <<= 1) {
            const float up = __shfl_up(scan, d, 64);
            if (lane >= d) scan += up;
        }

        // weight = trans_before*(1-e^-tau) = e^{-(scan-tau)} - e^{-scan}; ==0 when tau==0.
        lane_acc += ecarry * (expf(tau - scan) - expf(-scan)) * tt;

        const float total = __shfl(scan, 63, 64);   // chunk tau total (wave-uniform)
        ecarry *= expf(-total);
        if (ecarry < 1e-7f) break;   // residual weight < 1e-7*768*0.2m = 1.5e-4 m
    }

    // Wave-wide sum of contributions.
#pragma unroll
    for (int d = 32; d >= 1; d >>= 1) lane_acc += __shfl_xor(lane_acc, d, 64);

    if (lane == 0) {
        const float pred_m = lane_acc * VOXEL_F;
        const float gt_m   = gt_vox * VOXEL_F;
        const float diff = gt_m - pred_m;
        const float ad   = fabsf(diff);
        float* b = ws + 4 * (ray & (NBUCKET - 1));
        atomicAdd(&b[0], ad);
        atomicAdd(&b[1], 0.5f * diff * diff);
        atomicAdd(&b[2], ad / fmaxf(gt_m, 1e-6f));
        atomicAdd(&b[3], 1.0f);
    }
}

__global__ void finalize_kernel(const float* __restrict__ ws, float* __restrict__ out) {
    const int lane = (int)(threadIdx.x & 63);
    float a = ws[lane * 4 + 0];
    float b = ws[lane * 4 + 1];
    float c = ws[lane * 4 + 2];
    float n = ws[lane * 4 + 3];
#pragma unroll
    for (int d = 32; d >= 1; d >>= 1) {
        a += __shfl_xor(a, d, 64);
        b += __shfl_xor(b, d, 64);
        c += __shfl_xor(c, d, 64);
        n += __shfl_xor(n, d, 64);
    }
    if (lane == 0) {
        const float cnt = fmaxf(n, 1.0f);
        out[0] = a / cnt;
        out[1] = b / cnt;
        out[2] = c / cnt;
    }
}

extern "C" void kernel_launch(void* const* d_in, const int* in_sizes, int n_in,
                              void* d_out, int out_size, void* d_ws, size_t ws_size,
                              hipStream_t stream) {
    const float* grid    = (const float*)d_in[0];   // (1,5,32,512,512) fp32
    const float* origin  = (const float*)d_in[1];   // (1,5,3) fp32
    const float* points  = (const float*)d_in[2];   // (1,10000,3) fp32
    const int*   tindex  = (const int*)d_in[3];     // (1,10000) int32
    float* out = (float*)d_out;
    float* ws  = (float*)d_ws;

    zero_ws_kernel<<<1, NBUCKET * 4, 0, stream>>>(ws);

    const int waves_per_block = 256 / 64;                                 // 4 rays/block
    const int blocks = (N_RAYS + waves_per_block - 1) / waves_per_block;  // 2500
    render_rays_kernel<<<blocks, 256, 0, stream>>>(grid, origin, points, tindex, ws);

    finalize_kernel<<<1, 64, 0, stream>>>(ws, out);
}

// Round 3
// 216.462 us; speedup vs baseline: 3.3427x; 1.2742x over previous
//
#include <hip/hip_runtime.h>
#include <math.h>

#define T_DIM 5
#define Z_DIM 32
#define Y_DIM 512
#define X_DIM 512
#define N_RAYS 10000
#define N_STEPS 768
#define VOXEL_F 0.2f

// ws layout (floats): [0, 4*N_RAYS) per-ray float4 {|d|, .5d^2, absrel, 1.0};
//                     [4*N_RAYS, 5*N_RAYS) int permutation (rays sorted by tindex)
#define PERM_OFF (4 * N_RAYS)

// Single-block counting sort of ray ids by tindex (5 buckets).
// Groups same-origin rays so concurrently-resident render blocks share the
// same ~1.6 MB grid neighborhood -> per-XCD L2 residency.
__global__ __launch_bounds__(1024) void sort_rays_kernel(
    const int* __restrict__ tindex, int* __restrict__ perm)
{
    __shared__ int cnt[T_DIM];
    __shared__ int base[T_DIM];
    const int tid = threadIdx.x;
    if (tid < T_DIM) cnt[tid] = 0;
    __syncthreads();
    for (int i = tid; i < N_RAYS; i += 1024)
        atomicAdd(&cnt[tindex[i]], 1);
    __syncthreads();
    if (tid == 0) {
        int run = 0;
        for (int t = 0; t < T_DIM; ++t) { base[t] = run; run += cnt[t]; }
    }
    __syncthreads();
    for (int i = tid; i < N_RAYS; i += 1024) {
        const int pos = atomicAdd(&base[tindex[i]], 1);
        perm[pos] = i;
    }
}

// One wave per (sorted) ray. Iteration j covers steps [64j, 64j+64): lane L
// handles step 64j+L. Loop bounded by analytic box exit; early-out when
// transmittance < 1e-7 (residual weight < 1e-7*768*0.2 m = 1.5e-4 m).
__global__ __launch_bounds__(256) void render_rays_kernel(
    const float* __restrict__ grid,     // [T,Z,Y,X] raw feats (relu here)
    const float* __restrict__ origin,   // [T,3] meters
    const float* __restrict__ points,   // [N_RAYS,3] meters
    const int*   __restrict__ tindex,   // [N_RAYS]
    const int*   __restrict__ perm,     // [N_RAYS] sorted ray ids
    float*       __restrict__ loss4)    // [N_RAYS][4]
{
    const int wid  = (int)((blockIdx.x * blockDim.x + threadIdx.x) >> 6);
    const int lane = (int)(threadIdx.x & 63);
    if (wid >= N_RAYS) return;
    const int ray = perm[wid];

    const int ti = tindex[ray];
    const float ox = (origin[ti * 3 + 0] + 51.2f) * 5.0f;
    const float oy = (origin[ti * 3 + 1] + 51.2f) * 5.0f;
    const float oz = (origin[ti * 3 + 2] + 3.2f) * 5.0f;
    const float px = (points[ray * 3 + 0] + 51.2f) * 5.0f;
    const float py = (points[ray * 3 + 1] + 51.2f) * 5.0f;
    const float pz = (points[ray * 3 + 2] + 3.2f) * 5.0f;

    const float dx = px - ox, dy = py - oy, dz = pz - oz;
    const float gt_vox = sqrtf(dx * dx + dy * dy + dz * dz);
    const float inv = 1.0f / fmaxf(gt_vox, 1e-6f);
    const float ux = dx * inv, uy = dy * inv, uz = dz * inv;

    // Analytic exit t from box [0,X)x[0,Y)x[0,Z); origin is inside the box.
    // IEEE inf handles /0; fmaxf/fminf discard NaN (0/0). Per-step inb check
    // below still guards all edge cases exactly.
    float thi = 1e30f;
    thi = fminf(thi, fmaxf((0.0f - ox) / ux, ((float)X_DIM - ox) / ux));
    thi = fminf(thi, fmaxf((0.0f - oy) / uy, ((float)Y_DIM - oy) / uy));
    thi = fminf(thi, fmaxf((0.0f - oz) / uz, ((float)Z_DIM - oz) / uz));
    int n_active = (int)ceilf(fminf(thi, 769.0f) - 0.5f);  // steps k with k+0.5 < thi
    n_active = min(N_STEPS, max(0, n_active));
    const int iters = (n_active + 63) >> 6;

    const float* gbase = grid + (size_t)ti * (size_t)(Z_DIM * Y_DIM * X_DIM);

    float lane_acc = 0.0f;   // this lane's weighted-t contributions
    float ecarry   = 1.0f;   // exp(-sum tau of previous chunks), wave-uniform

    for (int j = 0; j < iters; ++j) {
        const int step = (j << 6) + lane;
        const float tt = (float)step + 0.5f;
        const float fx = fmaf(ux, tt, ox);
        const float fy = fmaf(uy, tt, oy);
        const float fz = fmaf(uz, tt, oz);
        const int ix = (int)floorf(fx);
        const int iy = (int)floorf(fy);
        const int iz = (int)floorf(fz);
        const bool inb = (ix >= 0) & (ix < X_DIM) & (iy >= 0) & (iy < Y_DIM) &
                         (iz >= 0) & (iz < Z_DIM);
        float tau = 0.0f;
        if ((step < n_active) && inb) {
            tau = fmaxf(gbase[((size_t)iz * Y_DIM + (size_t)iy) * X_DIM + (size_t)ix], 0.0f);
        }

        // Inclusive prefix sum of tau across lanes (steps are lane-ordered).
        float scan = tau;
#pragma unroll
        for (int d = 1; d < 64; d <<= 1) {
            const float up = __shfl_up(scan, d, 64);
            if (lane >= d) scan += up;
        }

        // weight = e^{-(scan-tau)} - e^{-scan}; exactly 0 when tau==0.
        lane_acc += ecarry * (expf(tau - scan) - expf(-scan)) * tt;

        const float total = __shfl(scan, 63, 64);   // chunk tau sum (uniform)
        ecarry *= expf(-total);
        if (ecarry < 1e-7f) break;
    }

    // Wave-wide sum of contributions.
#pragma unroll
    for (int d = 32; d >= 1; d >>= 1) lane_acc += __shfl_xor(lane_acc, d, 64);

    if (lane == 0) {
        const float pred_m = lane_acc * VOXEL_F;
        const float gt_m   = gt_vox * VOXEL_F;
        const float diff = gt_m - pred_m;
        const float ad   = fabsf(diff);
        float4 v;
        v.x = ad;
        v.y = 0.5f * diff * diff;
        v.z = ad / fmaxf(gt_m, 1e-6f);
        v.w = 1.0f;   // valid: gt >= 0 always (norm)
        reinterpret_cast<float4*>(loss4)[wid] = v;
    }
}

__global__ __launch_bounds__(1024) void finalize_kernel(
    const float* __restrict__ loss4, float* __restrict__ out)
{
    const int tid  = (int)threadIdx.x;
    const int lane = tid & 63;
    const int wv   = tid >> 6;
    float a = 0.0f, b = 0.0f, c = 0.0f, n = 0.0f;
    for (int i = tid; i < N_RAYS; i += 1024) {
        const float4 v = reinterpret_cast<const float4*>(loss4)[i];
        a += v.x; b += v.y; c += v.z; n += v.w;
    }
#pragma unroll
    for (int d = 32; d >= 1; d >>= 1) {
        a += __shfl_xor(a, d, 64);
        b += __shfl_xor(b, d, 64);
        c += __shfl_xor(c, d, 64);
        n += __shfl_xor(n, d, 64);
    }
    __shared__ float red[16][4];
    if (lane == 0) { red[wv][0] = a; red[wv][1] = b; red[wv][2] = c; red[wv][3] = n; }
    __syncthreads();
    if (wv == 0 && lane < 16) {
        a = red[lane][0]; b = red[lane][1]; c = red[lane][2]; n = red[lane][3];
#pragma unroll
        for (int d = 8; d >= 1; d >>= 1) {
            a += __shfl_xor(a, d, 64);
            b += __shfl_xor(b, d, 64);
            c += __shfl_xor(c, d, 64);
            n += __shfl_xor(n, d, 64);
        }
        if (lane == 0) {
            const float cnt = fmaxf(n, 1.0f);
            out[0] = a / cnt;
            out[1] = b / cnt;
            out[2] = c / cnt;
        }
    }
}

extern "C" void kernel_launch(void* const* d_in, const int* in_sizes, int n_in,
                              void* d_out, int out_size, void* d_ws, size_t ws_size,
                              hipStream_t stream) {
    const float* grid    = (const float*)d_in[0];   // (1,5,32,512,512) fp32
    const float* origin  = (const float*)d_in[1];   // (1,5,3) fp32
    const float* points  = (const float*)d_in[2];   // (1,10000,3) fp32
    const int*   tindex  = (const int*)d_in[3];     // (1,10000) int32
    float* out   = (float*)d_out;
    float* ws    = (float*)d_ws;
    float* loss4 = ws;
    int*   perm  = (int*)(ws + PERM_OFF);

    sort_rays_kernel<<<1, 1024, 0, stream>>>(tindex, perm);

    const int waves_per_block = 256 / 64;                                 // 4 rays/block
    const int blocks = (N_RAYS + waves_per_block - 1) / waves_per_block;  // 2500
    render_rays_kernel<<<blocks, 256, 0, stream>>>(grid, origin, points, tindex, perm, loss4);

    finalize_kernel<<<1, 1024, 0, stream>>>(loss4, out);
}